// Round 7
// baseline (212.807 us; speedup 1.0000x reference)
//
#include <hip/hip_runtime.h>
#include <math.h>
#include <stdint.h>

// tgate_hybrid: B=4,S=4096,DIMS=2048,T=10,K=2.
// R19: vmem-free k-loop + occupancy. R18 audit: frag refills issued inside
// the loop are YOUNGER than in-flight staging chunks; the compiler's wait
// before each F-use is vmcnt(#younger)=small, and in-order retirement makes
// it drain ALL older staging -> every "pipelined" variant (R12..R18)
// actually ran at depth ~1. Invariant: any in-loop frag vmem collapses the
// staging pipeline. Also R16 arithmetic: even fully LLC-warm the loop body
// costs ~56us vs ~12us for its bytes -> body-stall dominated; occupancy
// stuck at 19.7% (2 blocks/CU). Fix: block = 1024 threads (16 waves),
// 16 rows; each wave owns K=128 (4 k-steps), preloads its 16 B-fragments
// into 64 VGPRs BEFORE the loop, stages its 16x128 x-slice as 2 chunks.
// The k-loop has ZERO vmem instructions -- only two monotone vmcnt waits
// against staging; nothing can drain. LDS 130KB -> 1 block/CU = 16 waves
// (50% occupancy). Per-step math verbatim (same f[8], hi/lo split, 6-MFMA
// order); fold now sums 16 slices of 4 k-steps (was 8 of 8) -- pure f32
// reassociation ~1e-7, dominated by the unchanged 2^-8 bf16-split error.
// Predict: k1 ~83 -> ~30-40us, total -> ~160-175us, absmax ~0.0039.

#define NROWS   16384
#define DIMS_   2048
#define TT      10

typedef __attribute__((ext_vector_type(8))) short short8;
typedef __attribute__((ext_vector_type(4))) float f32x4;

__device__ __forceinline__ unsigned short bf16_rne(float f) {
    unsigned int u = __float_as_uint(f);
    unsigned int r = u + 0x7fffu + ((u >> 16) & 1u);
    return (unsigned short)(r >> 16);
}

// ---- k0: build B fragments (unchanged since R5; must stay identical).
__global__ __launch_bounds__(256)
void tgate_k0(const float* __restrict__ W_cls,
              const float* __restrict__ W_sparse,
              const float* __restrict__ W_gates,
              unsigned short* __restrict__ frag)
{
    int t = blockIdx.x * 256 + threadIdx.x;
    int K0   = t >> 7;
    int nt   = (t >> 6) & 1;
    int lane = t & 63;
    int n  = nt * 16 + (lane & 15);
    int kb = K0 * 32 + (lane >> 4) * 8;
    short8 hi, lo;
    #pragma unroll
    for (int j = 0; j < 8; ++j) {
        int k = kb + j;
        float w = 0.0f;
        if (n < 10)      w = W_cls[k * TT + n];
        else if (n < 20) w = W_sparse[k * TT + n - 10];
        else if (n < 30) w = W_gates[k * TT + n - 20];
        unsigned short h = bf16_rne(w);
        float back = __uint_as_float(((unsigned int)h) << 16);
        hi[j] = (short)h;
        lo[j] = (short)bf16_rne(w - back);
    }
    short8* fv = reinterpret_cast<short8*>(frag);
    fv[(K0 * 4 + nt * 2 + 0) * 64 + lane] = hi;
    fv[(K0 * 4 + nt * 2 + 1) * 64 + lane] = lo;
}

// one chunk: 16 rows x 64 cols = 4 KB via 4 async 1-KB instrs (4 rows each);
// verified R12/R18 layout: instr t -> rows 4t..4t+3, LDS bufbase + t*260.
__device__ __forceinline__ void issue_chunk(const float* __restrict__ x,
                                            float* bufbase, int row0, int lane,
                                            int colf0)
{
    #pragma unroll
    for (int t = 0; t < 4; ++t) {
        const float* gp = x + (size_t)(row0 + 4 * t + (lane >> 4)) * DIMS_
                            + colf0 + (lane & 15) * 4;
        __builtin_amdgcn_global_load_lds(
            (const __attribute__((address_space(1))) void*)gp,
            (__attribute__((address_space(3))) void*)(bufbase + t * 260),
            16, 0, 0);
    }
}

// ---- k1: 16-wave block; per-wave K=128, frags VGPR-resident, vmem-free loop
__global__ __launch_bounds__(1024, 4)
void tgate_k1(const float* __restrict__ x,
              const unsigned short* __restrict__ frag,
              const float* __restrict__ b_cls,
              const float* __restrict__ b_sparse,
              const float* __restrict__ b_gates,
              const float* __restrict__ alpha,
              float* __restrict__ out)
{
    // 16 waves x 2 chunks x 1040 floats = 133120 B; red/fold aliases after.
    __shared__ alignas(16) float smem[16 * 2080];

    const int tid   = threadIdx.x;
    const int lane  = tid & 63;
    const int wv    = __builtin_amdgcn_readfirstlane(tid >> 6);   // 0..15
    const int row0  = blockIdx.x * 16;
    const int m     = lane & 15;
    const int quad  = lane >> 4;
    const int cbase = wv * 128;          // wave's contiguous 128-col K-span

    float* bufs = smem + wv * 2080;      // chunk c at bufs + c*1040
    const short8* fv    = reinterpret_cast<const short8*>(frag);
    const short8* fbase = fv + (4 * wv * 4) * 64 + lane;  // step p -> (p*4+j)*64

    f32x4 accA = (f32x4){0.f, 0.f, 0.f, 0.f};   // n = 0..15
    f32x4 accB = (f32x4){0.f, 0.f, 0.f, 0.f};   // n = 16..31

    // ---- frag preload FIRST (oldest vmem; retired by the vmcnt(4) below)
    short8 F[4][4];
    #pragma unroll
    for (int p = 0; p < 4; ++p) {
        #pragma unroll
        for (int j = 0; j < 4; ++j)
            F[p][j] = fbase[(p * 4 + j) * 64];
    }
    __builtin_amdgcn_sched_barrier(0);
    // ---- stage both chunks (8 loads); pipeline: frags+c0 land -> compute c0
    issue_chunk(x, bufs,        row0, lane, cbase);
    issue_chunk(x, bufs + 1040, row0, lane, cbase + 64);
    __builtin_amdgcn_sched_barrier(0);

    __builtin_amdgcn_s_waitcnt(0x0F74);  // vmcnt(4): frags + chunk0 landed
    __builtin_amdgcn_sched_barrier(0);

    #pragma unroll
    for (int c = 0; c < 2; ++c) {
        if (c == 1) {
            __builtin_amdgcn_s_waitcnt(0x0F70);  // vmcnt(0): chunk1 landed
            __builtin_amdgcn_sched_barrier(0);
        }
        const float* Lbuf = bufs + c * 1040;
        #pragma unroll
        for (int u = 0; u < 2; ++u) {
            const int p = 2 * c + u;             // k-step within wave (0..3)
            const float* src = Lbuf + (m >> 2) * 260 + (m & 3) * 64
                                    + u * 32 + quad * 8;
            float4 b0 = *reinterpret_cast<const float4*>(src);
            float4 b1 = *reinterpret_cast<const float4*>(src + 4);
            float f[8] = {b0.x, b0.y, b0.z, b0.w, b1.x, b1.y, b1.z, b1.w};
            short8 ah, al;
            #pragma unroll
            for (int j = 0; j < 8; ++j) {
                unsigned short hh = bf16_rne(f[j]);           // rne hi (R5.. path)
                float back = __uint_as_float(((unsigned int)hh) << 16);
                ah[j] = (short)hh;
                al[j] = (short)bf16_rne(f[j] - back);
            }
            short8 h0 = F[p][0], l0 = F[p][1], h1 = F[p][2], l1 = F[p][3];

            accA = __builtin_amdgcn_mfma_f32_16x16x32_bf16(ah, h0, accA, 0, 0, 0);
            accA = __builtin_amdgcn_mfma_f32_16x16x32_bf16(al, h0, accA, 0, 0, 0);
            accA = __builtin_amdgcn_mfma_f32_16x16x32_bf16(ah, l0, accA, 0, 0, 0);
            accB = __builtin_amdgcn_mfma_f32_16x16x32_bf16(ah, h1, accB, 0, 0, 0);
            accB = __builtin_amdgcn_mfma_f32_16x16x32_bf16(al, h1, accB, 0, 0, 0);
            accB = __builtin_amdgcn_mfma_f32_16x16x32_bf16(ah, l1, accB, 0, 0, 0);
        }
    }

    // ---- partials to LDS: red[s][row][j], s = wv (16 slices), pitch 33
    float* red = smem;
    __syncthreads();
    #pragma unroll
    for (int r = 0; r < 4; ++r) {
        int row = quad * 4 + r;           // C/D layout (verified m89)
        red[(wv * 16 + row) * 33 + m]      = accA[r];
        red[(wv * 16 + row) * 33 + m + 16] = accB[r];
    }
    __syncthreads();

    // ---- fold: s = 0..15 ascending (16 slices of 4 k-steps each)
    float* fold = red + 16 * 16 * 33;
    if (tid < 256) {
        #pragma unroll
        for (int u = 0; u < 2; ++u) {
            int i = tid * 2 + u;
            int row = i >> 5, j = i & 31;
            float a = 0.0f;
            #pragma unroll
            for (int s = 0; s < 16; ++s) a += red[(s * 16 + row) * 33 + j];
            fold[row * 33 + j] = a;
        }
    }
    __syncthreads();

    // ---- epilogue: lanes 0..15 of wave 0 (verbatim since R5)
    if (tid < 16) {
        const float* l = &fold[tid * 33];
        float lc[TT], lsp[TT], g[TT];
        #pragma unroll
        for (int t = 0; t < TT; ++t) {
            lc[t]  = l[t]      + b_cls[t];
            lsp[t] = l[10 + t] + b_sparse[t];
            float lg = l[20 + t] + b_gates[t];
            g[t] = 1.0f / (1.0f + __expf(-lg));
        }
        float mm = lc[0];
        #pragma unroll
        for (int t = 1; t < TT; ++t) mm = fmaxf(mm, lc[t]);
        float esum = 0.0f, gdot = 0.0f;
        #pragma unroll
        for (int t = 0; t < TT; ++t) {
            float e = __expf(lc[t] - mm);
            esum += e;
            gdot = fmaf(g[t], e, gdot);
        }
        float v1 = lsp[0], v2 = -1e30f, gv1 = g[0], gv2 = 0.0f;
        #pragma unroll
        for (int t = 1; t < TT; ++t) {
            if (lsp[t] > v1)      { v2 = v1; gv2 = gv1; v1 = lsp[t]; gv1 = g[t]; }
            else if (lsp[t] > v2) { v2 = lsp[t]; gv2 = g[t]; }
        }
        float s1 = 1.0f / (1.0f + __expf(v2 - v1));
        float s2 = 1.0f - s1;
        float a  = 1.0f / (1.0f + __expf(-alpha[0]));
        float sparse_dot = fmaf(gv1, s1, gv2 * s2);
        out[row0 + tid] = fmaf(a, sparse_dot, (1.0f - a) * (gdot / esum));
    }
}

extern "C" void kernel_launch(void* const* d_in, const int* in_sizes, int n_in,
                              void* d_out, int out_size, void* d_ws, size_t ws_size,
                              hipStream_t stream) {
    const float* x        = (const float*)d_in[0];
    const float* W_cls    = (const float*)d_in[1];
    const float* b_cls    = (const float*)d_in[2];
    const float* W_sparse = (const float*)d_in[3];
    const float* b_sparse = (const float*)d_in[4];
    const float* W_gates  = (const float*)d_in[5];
    const float* b_gates  = (const float*)d_in[6];
    const float* alpha    = (const float*)d_in[7];
    float* out = (float*)d_out;

    unsigned short* frag = (unsigned short*)d_ws;   // 256 KB

    tgate_k0<<<dim3(32), dim3(256), 0, stream>>>(W_cls, W_sparse, W_gates, frag);
    tgate_k1<<<dim3(NROWS / 16), dim3(1024), 0, stream>>>(x, frag, b_cls, b_sparse,
                                                          b_gates, alpha, out);
}

// Round 8
// 207.292 us; speedup vs baseline: 1.0266x; 1.0266x over previous
//
#include <hip/hip_runtime.h>
#include <math.h>
#include <stdint.h>

// tgate_hybrid: B=4,S=4096,DIMS=2048,T=10,K=2.
// R20: persistent cross-tile register pipeline. Accounting after R19: per-CU
// issue time ~6us (matches VALUBusy 8.6%), ideal read ~21us, yet k1 ~80us
// with all pipes <10% -> waves wait on vmem ~90% of the time. Every ~80us
// variant shared one property: its prefetch queue drained to ~empty each
// step (R13/R18 via frag-wait drains; R14/R15/R17 via vmcnt(0) per chunk;
// R19 via block-boundary = 1-tile-deep pipeline + 4 sequential block
// rounds) -> chip-wide memory duty ~25%. R16's 11 TB/s diag is the
// counterexample: back-to-back loads, never drained. Fix actually never
// tried: persistent blocks (256 = 1/CU, 4 tiles each), frags VGPR-resident
// (loaded once; also cuts 256MB->64MB frag re-read traffic), x direct to
// registers in MFMA A-layout (16 rows x one full 128B line per step,
// coalesced), 3-slot ring, prefetch distance 2, counted waits vmcnt(4/2/0)
// ONLY; tile-boundary fold uses raw s_barrier + lgkmcnt(0) (no vmcnt
// drain) so next-tile loads stay in flight across fold/epilogue.
// Math verbatim R19 (verified absmax exactly 0.00390625): same f[8],
// hi/lo split, 6-MFMA order, 16-slice ascending fold, epilogue ->
// bit-identical output.

#define NROWS   16384
#define DIMS_   2048
#define TT      10
#define TPB     4      // tiles per block; grid = 1024/TPB = 256 = 1/CU

typedef __attribute__((ext_vector_type(8))) short short8;
typedef __attribute__((ext_vector_type(4))) float f32x4;

__device__ __forceinline__ unsigned short bf16_rne(float f) {
    unsigned int u = __float_as_uint(f);
    unsigned int r = u + 0x7fffu + ((u >> 16) & 1u);
    return (unsigned short)(r >> 16);
}

// ---- k0: build B fragments (unchanged since R5; must stay identical).
__global__ __launch_bounds__(256)
void tgate_k0(const float* __restrict__ W_cls,
              const float* __restrict__ W_sparse,
              const float* __restrict__ W_gates,
              unsigned short* __restrict__ frag)
{
    int t = blockIdx.x * 256 + threadIdx.x;
    int K0   = t >> 7;
    int nt   = (t >> 6) & 1;
    int lane = t & 63;
    int n  = nt * 16 + (lane & 15);
    int kb = K0 * 32 + (lane >> 4) * 8;
    short8 hi, lo;
    #pragma unroll
    for (int j = 0; j < 8; ++j) {
        int k = kb + j;
        float w = 0.0f;
        if (n < 10)      w = W_cls[k * TT + n];
        else if (n < 20) w = W_sparse[k * TT + n - 10];
        else if (n < 30) w = W_gates[k * TT + n - 20];
        unsigned short h = bf16_rne(w);
        float back = __uint_as_float(((unsigned int)h) << 16);
        hi[j] = (short)h;
        lo[j] = (short)bf16_rne(w - back);
    }
    short8* fv = reinterpret_cast<short8*>(frag);
    fv[(K0 * 4 + nt * 2 + 0) * 64 + lane] = hi;
    fv[(K0 * 4 + nt * 2 + 1) * 64 + lane] = lo;
}

// ---- k1: persistent 16-wave blocks; per-wave K=128; frags VGPR-resident;
//      x direct-to-register (MFMA A-layout), 3-slot ring, counted waits.
__global__ __launch_bounds__(1024, 4)
void tgate_k1(const float* __restrict__ x,
              const unsigned short* __restrict__ frag,
              const float* __restrict__ b_cls,
              const float* __restrict__ b_sparse,
              const float* __restrict__ b_gates,
              const float* __restrict__ alpha,
              float* __restrict__ out)
{
    // LDS only for fold: red[16][16][33] + fold[16][33] = 35904 B
    __shared__ alignas(16) float red_lds[16 * 16 * 33 + 16 * 33];

    const int tid   = threadIdx.x;
    const int lane  = tid & 63;
    const int wv    = __builtin_amdgcn_readfirstlane(tid >> 6);   // 0..15
    const int m     = lane & 15;
    const int quad  = lane >> 4;
    const int t0    = blockIdx.x * TPB;   // first tile of this block

    const short8* fv    = reinterpret_cast<const short8*>(frag);
    const short8* fbase = fv + (4 * wv * 4) * 64 + lane;  // step p -> (p*4+j)*64

    // ---- frag preload (16 loads/wave, oldest vmem; drained at iter 0 wait)
    short8 F[4][4];
    #pragma unroll
    for (int p = 0; p < 4; ++p) {
        #pragma unroll
        for (int j = 0; j < 4; ++j)
            F[p][j] = fbase[(p * 4 + j) * 64];
    }
    __builtin_amdgcn_sched_barrier(0);

    // ---- x ring: 3 slots, prefetch distance 2. Step g (0..15): tile
    //      t0+(g>>2), local k-step g&3; lane reads row m, 32B at its MFMA
    //      A-fragment position (full 128B line per row per step, coalesced).
    float4 xa[3], xb[3];
    #define ISSUE(g)                                                          \
    {                                                                         \
        const int tt_ = (g) >> 2, pp_ = (g) & 3;                              \
        const float* sp_ = x + (size_t)((t0 + tt_) * 16 + m) * DIMS_          \
                             + wv * 128 + pp_ * 32 + quad * 8;                \
        xa[(g) % 3] = *reinterpret_cast<const float4*>(sp_);                  \
        xb[(g) % 3] = *reinterpret_cast<const float4*>(sp_ + 4);              \
    }
    ISSUE(0)
    ISSUE(1)
    __builtin_amdgcn_sched_barrier(0);

    f32x4 accA = (f32x4){0.f, 0.f, 0.f, 0.f};   // n = 0..15
    f32x4 accB = (f32x4){0.f, 0.f, 0.f, 0.f};   // n = 16..31

    float* red  = red_lds;
    float* fold = red_lds + 16 * 16 * 33;

    #pragma unroll
    for (int g = 0; g < 16; ++g) {
        if (g + 2 < 16) { ISSUE(g + 2) }          // issue-early, slot (g+2)%3
        __builtin_amdgcn_sched_barrier(0);
        // counted wait for step g: younger = in-flight prefetches only
        if (g < 14)       __builtin_amdgcn_s_waitcnt(0x0F74);  // vmcnt(4)
        else if (g == 14) __builtin_amdgcn_s_waitcnt(0x0F72);  // vmcnt(2)
        else              __builtin_amdgcn_s_waitcnt(0x0F70);  // vmcnt(0)
        __builtin_amdgcn_sched_barrier(0);

        const int p = g & 3;                      // compile-time after unroll
        float4 b0 = xa[g % 3];
        float4 b1 = xb[g % 3];
        float f[8] = {b0.x, b0.y, b0.z, b0.w, b1.x, b1.y, b1.z, b1.w};
        short8 ah, al;
        #pragma unroll
        for (int j = 0; j < 8; ++j) {
            unsigned short hh = bf16_rne(f[j]);               // rne hi (R5.. path)
            float back = __uint_as_float(((unsigned int)hh) << 16);
            ah[j] = (short)hh;
            al[j] = (short)bf16_rne(f[j] - back);
        }
        short8 h0 = F[p][0], l0 = F[p][1], h1 = F[p][2], l1 = F[p][3];

        accA = __builtin_amdgcn_mfma_f32_16x16x32_bf16(ah, h0, accA, 0, 0, 0);
        accA = __builtin_amdgcn_mfma_f32_16x16x32_bf16(al, h0, accA, 0, 0, 0);
        accA = __builtin_amdgcn_mfma_f32_16x16x32_bf16(ah, l0, accA, 0, 0, 0);
        accB = __builtin_amdgcn_mfma_f32_16x16x32_bf16(ah, h1, accB, 0, 0, 0);
        accB = __builtin_amdgcn_mfma_f32_16x16x32_bf16(al, h1, accB, 0, 0, 0);
        accB = __builtin_amdgcn_mfma_f32_16x16x32_bf16(ah, l1, accB, 0, 0, 0);

        if (p == 3) {
            // ---- tile finish (tile t0 + (g>>2)); raw barriers only --
            //      in-flight next-tile x loads survive (no vmcnt drain).
            const int tile = t0 + (g >> 2);
            #pragma unroll
            for (int r = 0; r < 4; ++r) {
                int row = quad * 4 + r;           // C/D layout (verified m89)
                red[(wv * 16 + row) * 33 + m]      = accA[r];
                red[(wv * 16 + row) * 33 + m + 16] = accB[r];
            }
            __builtin_amdgcn_s_waitcnt(0xC07F);   // lgkmcnt(0): red visible
            __builtin_amdgcn_sched_barrier(0);
            __builtin_amdgcn_s_barrier();

            // fold: s = 0..15 ascending (verbatim R19; bit-identical)
            if (tid < 256) {
                #pragma unroll
                for (int u = 0; u < 2; ++u) {
                    int i = tid * 2 + u;
                    int row = i >> 5, j = i & 31;
                    float a = 0.0f;
                    #pragma unroll
                    for (int s = 0; s < 16; ++s) a += red[(s * 16 + row) * 33 + j];
                    fold[row * 33 + j] = a;
                }
            }
            __builtin_amdgcn_s_waitcnt(0xC07F);   // lgkmcnt(0): fold visible
            __builtin_amdgcn_sched_barrier(0);
            __builtin_amdgcn_s_barrier();

            // epilogue: lanes 0..15 of wave 0 (verbatim since R5)
            if (tid < 16) {
                const float* l = &fold[tid * 33];
                float lc[TT], lsp[TT], gg[TT];
                #pragma unroll
                for (int t = 0; t < TT; ++t) {
                    lc[t]  = l[t]      + b_cls[t];
                    lsp[t] = l[10 + t] + b_sparse[t];
                    float lg = l[20 + t] + b_gates[t];
                    gg[t] = 1.0f / (1.0f + __expf(-lg));
                }
                float mm = lc[0];
                #pragma unroll
                for (int t = 1; t < TT; ++t) mm = fmaxf(mm, lc[t]);
                float esum = 0.0f, gdot = 0.0f;
                #pragma unroll
                for (int t = 0; t < TT; ++t) {
                    float e = __expf(lc[t] - mm);
                    esum += e;
                    gdot = fmaf(gg[t], e, gdot);
                }
                float v1 = lsp[0], v2 = -1e30f, gv1 = gg[0], gv2 = 0.0f;
                #pragma unroll
                for (int t = 1; t < TT; ++t) {
                    if (lsp[t] > v1)      { v2 = v1; gv2 = gv1; v1 = lsp[t]; gv1 = gg[t]; }
                    else if (lsp[t] > v2) { v2 = lsp[t]; gv2 = gg[t]; }
                }
                float s1 = 1.0f / (1.0f + __expf(v2 - v1));
                float s2 = 1.0f - s1;
                float a  = 1.0f / (1.0f + __expf(-alpha[0]));
                float sparse_dot = fmaf(gv1, s1, gv2 * s2);
                out[tile * 16 + tid] = fmaf(a, sparse_dot, (1.0f - a) * (gdot / esum));
            }

            accA = (f32x4){0.f, 0.f, 0.f, 0.f};
            accB = (f32x4){0.f, 0.f, 0.f, 0.f};
        }
    }
    #undef ISSUE
}

extern "C" void kernel_launch(void* const* d_in, const int* in_sizes, int n_in,
                              void* d_out, int out_size, void* d_ws, size_t ws_size,
                              hipStream_t stream) {
    const float* x        = (const float*)d_in[0];
    const float* W_cls    = (const float*)d_in[1];
    const float* b_cls    = (const float*)d_in[2];
    const float* W_sparse = (const float*)d_in[3];
    const float* b_sparse = (const float*)d_in[4];
    const float* W_gates  = (const float*)d_in[5];
    const float* b_gates  = (const float*)d_in[6];
    const float* alpha    = (const float*)d_in[7];
    float* out = (float*)d_out;

    unsigned short* frag = (unsigned short*)d_ws;   // 256 KB

    tgate_k0<<<dim3(32), dim3(256), 0, stream>>>(W_cls, W_sparse, W_gates, frag);
    tgate_k1<<<dim3(NROWS / 16 / TPB), dim3(1024), 0, stream>>>(
        x, frag, b_cls, b_sparse, b_gates, alpha, out);
}